// Round 14
// baseline (493.812 us; speedup 1.0000x reference)
//
#include <hip/hip_runtime.h>
#include <cstddef>

typedef __attribute__((ext_vector_type(8))) short short8;
typedef __attribute__((ext_vector_type(4))) float floatx4;

// ---------------------------------------------------------------- bf16 utils
__device__ __forceinline__ unsigned short f2bf(float f) {
  union { float f; unsigned u; } v; v.f = f;
  const unsigned r = v.u + 0x7fffu + ((v.u >> 16) & 1u);  // RNE
  return (unsigned short)(r >> 16);
}

// ---------------------------------------------------------------- reductions
__device__ __forceinline__ float block_reduce_sum(float v, float* sm) {
#pragma unroll
  for (int off = 32; off > 0; off >>= 1) v += __shfl_down(v, off, 64);
  const int lane = threadIdx.x & 63, wid = threadIdx.x >> 6;
  __syncthreads();
  if (lane == 0) sm[wid] = v;
  __syncthreads();
  if (threadIdx.x == 0) {
    float t = 0.f;
    const int nw = (blockDim.x + 63) >> 6;
    for (int i = 0; i < nw; ++i) t += sm[i];
    sm[0] = t;
  }
  __syncthreads();
  return sm[0];
}

// ---------------------------------------------------------------- ternarize
// red[t*4+0]=sum|w|, red[t*4+1]=masked count, red[t*4+2]=masked sum|w|.
__device__ __forceinline__ void tsel(int t, const float* w0, const float* w1,
                                     const float* w2, const float* w3, int n0,
                                     int n1, int n2, int n3,
                                     const float*& w, int& n) {
  w = (t == 0) ? w0 : (t == 1) ? w1 : (t == 2) ? w2 : w3;
  n = (t == 0) ? n0 : (t == 1) ? n1 : (t == 2) ? n2 : n3;
}

__global__ __launch_bounds__(256) void tern_phase1(
    const float* w0, const float* w1, const float* w2, const float* w3,
    int n0, int n1, int n2, int n3, float* __restrict__ red) {
  __shared__ float sm[8];
  const float* w; int n;
  tsel(blockIdx.y, w0, w1, w2, w3, n0, n1, n2, n3, w, n);
  if ((int)blockIdx.x * 256 >= n) return;
  const int i = blockIdx.x * 256 + threadIdx.x;
  float s = (i < n) ? fabsf(w[i]) : 0.f;
  s = block_reduce_sum(s, sm);
  if (threadIdx.x == 0) atomicAdd(&red[blockIdx.y * 4 + 0], s);
}

// phase2: alpha sums AND all weight packing (reuses the loaded value).
// bp1: conv1 signs, K=32 (27 taps + 5 zeros from memset), k=ic*9+kh*3+kw,
//      dest ((k>>3)*32 + oc)*8 + (k&7)  -> lane B/A-frag = one 16B load
// bp2/bp3: bf16 sign, k=(kh*3+kw)*CIN+ic, dest ((k>>3)*COUT+n)*8+(k&7)
// ql: fp32 sign (alpha applied in linear via red)
__global__ __launch_bounds__(256) void tern_phase2(
    const float* w0, const float* w1, const float* w2, const float* w3,
    int n0, int n1, int n2, int n3, float* __restrict__ red,
    unsigned short* __restrict__ bp1, unsigned short* __restrict__ bp2,
    unsigned short* __restrict__ bp3, float* __restrict__ ql) {
  __shared__ float sm[8];
  const float* w; int n;
  const int by = blockIdx.y;
  tsel(by, w0, w1, w2, w3, n0, n1, n2, n3, w, n);
  if ((int)blockIdx.x * 256 >= n) return;
  const float delta = 0.7f * red[by * 4 + 0] / (float)n;
  const int i = blockIdx.x * 256 + threadIdx.x;
  float c = 0.f, a = 0.f;
  float wv = 0.f;
  if (i < n) {
    wv = w[i];
    const float av = fabsf(wv);
    if (av > delta) { c = 1.f; a = av; }
  }
  // ---- pack (independent of the reductions)
  if (i < n) {
    const float sgnf = (wv > delta) ? 1.f : (wv < -delta ? -1.f : 0.f);
    const unsigned short sgnb =
        (wv > delta) ? 0x3F80u : (wv < -delta ? 0xBF80u : 0u);
    if (by == 0) {
      const int k = i % 27, oc = i / 27;  // w1 OIHW flat: oc*27 + (ic*9+kh*3+kw)
      bp1[((size_t)(k >> 3) * 32 + oc) * 8 + (k & 7)] = sgnb;
    } else if (by == 1) {
      const int k = (i % 9) * 32 + (i % 288) / 9;
      bp2[((size_t)(k >> 3) * 64 + i / 288) * 8 + (k & 7)] = sgnb;
    } else if (by == 2) {
      const int k = (i % 9) * 64 + (i % 576) / 9;
      bp3[((size_t)(k >> 3) * 128 + i / 576) * 8 + (k & 7)] = sgnb;
    } else {
      ql[i] = sgnf;
    }
  }
  c = block_reduce_sum(c, sm);
  a = block_reduce_sum(a, sm);
  if (threadIdx.x == 0) {
    atomicAdd(&red[by * 4 + 1], c);
    atomicAdd(&red[by * 4 + 2], a);
  }
}

// ---------------------------------------------------------------- conv1 (MFMA)
// Implicit GEMM: block = 8x16 output px tile of one image (grid 98 x 64).
// R25: stage converts fp32->bf16 ONCE (1683 f2bf) instead of per-im2col-elem
// (4096 f2bf) — im2col is now pure u16 copy. Bit-identical output (same
// f2bf on same values, applied earlier). LDS 3368+10240 = 13.6KB.
__global__ __launch_bounds__(256) void conv1_mfma(
    const float* __restrict__ x, const unsigned short* __restrict__ bp1,
    const float* __restrict__ g1, const float* __restrict__ b1,
    const float* __restrict__ m1, const float* __restrict__ v1,
    const float* __restrict__ red, unsigned short* __restrict__ y) {
  __shared__ unsigned short xsb[3 * 17 * 33 + 1];  // 3368 B (bf16 patch)
  __shared__ unsigned short im[128 * 40];          // 10240 B
  const int n = blockIdx.y;
  const int oh0 = (blockIdx.x / 7) * 8, ow0 = (blockIdx.x % 7) * 16;
  const int t = threadIdx.x;
  const int wave = t >> 6, lane = t & 63, quad = lane >> 4, l16 = lane & 15;

  // ---- stage input patch as bf16 (zeros outside image); pad=1, stride=2
  const int ihb = oh0 * 2 - 1, iwb = ow0 * 2 - 1;
  for (int i = t; i < 1683; i += 256) {
    const int ic = i / 561, r2 = i % 561;
    const int pr = r2 / 33, pc = r2 % 33;
    const int ih = ihb + pr, iw = iwb + pc;
    float v = 0.f;
    if ((unsigned)ih < 224u && (unsigned)iw < 224u)
      v = x[((size_t)n * 3 + ic) * 50176 + (size_t)ih * 224 + iw];
    xsb[i] = f2bf(v);
  }
  __syncthreads();

  // ---- im2col: chunk = (px, seg) -> 8 bf16 k-values, one 16B write
#pragma unroll
  for (int cc = 0; cc < 2; ++cc) {
    const int c = cc * 256 + t;
    const int px = c >> 2, seg = c & 3;
    const int ohl = px >> 4, owl = px & 15;
    unsigned u[4];
#pragma unroll
    for (int jj = 0; jj < 4; ++jj) {
      unsigned short lo = 0, hi = 0;
      const int k0 = seg * 8 + 2 * jj, k1 = k0 + 1;
      if (k0 < 27) {
        const int ic = k0 / 9, tp = k0 % 9;
        lo = xsb[(ic * 17 + ohl * 2 + tp / 3) * 33 + owl * 2 + tp % 3];
      }
      if (k1 < 27) {
        const int ic = k1 / 9, tp = k1 % 9;
        hi = xsb[(ic * 17 + ohl * 2 + tp / 3) * 33 + owl * 2 + tp % 3];
      }
      u[jj] = (unsigned)lo | ((unsigned)hi << 16);
    }
    *(uint4*)(&im[px * 40 + seg * 8]) = make_uint4(u[0], u[1], u[2], u[3]);
  }

  // ---- B fragments (k = quad*8+j, n = nf*16+l16)
  short8 bfr[2];
#pragma unroll
  for (int nf = 0; nf < 2; ++nf)
    bfr[nf] = *(const short8*)(bp1 + ((size_t)quad * 32 + nf * 16 + l16) * 8);

  floatx4 acc[2][2];
#pragma unroll
  for (int mi = 0; mi < 2; ++mi) {
    acc[mi][0] = (floatx4){0.f, 0.f, 0.f, 0.f};
    acc[mi][1] = (floatx4){0.f, 0.f, 0.f, 0.f};
  }
  __syncthreads();

#pragma unroll
  for (int mi = 0; mi < 2; ++mi) {
    const int pxb = (wave * 2 + mi) * 16;
    const short8 a = *(const short8*)(&im[(pxb + l16) * 40 + quad * 8]);
#pragma unroll
    for (int nf = 0; nf < 2; ++nf)
      acc[mi][nf] = __builtin_amdgcn_mfma_f32_16x16x32_bf16(
          a, bfr[nf], acc[mi][nf], 0, 0, 0);
  }

  // ---- epilogue: BN1 (inline fold) + ReLU -> LDS (reuse im) -> coalesced
  const float alpha1 = red[2] / fmaxf(red[1], 1.f);
  float sc[2], bs[2];
#pragma unroll
  for (int nf = 0; nf < 2; ++nf) {
    const int ch = nf * 16 + l16;
    const float inv = g1[ch] / sqrtf(v1[ch] + 1e-5f);
    sc[nf] = alpha1 * inv;
    bs[nf] = b1[ch] - m1[ch] * inv;
  }
  __syncthreads();  // all waves' A-frag reads of im complete
  // st layout: [px][40 ushorts] (32 ch + 8 pad), ch XOR-swizzled by quad
#pragma unroll
  for (int mi = 0; mi < 2; ++mi) {
    const int ohl = wave * 2 + mi;
#pragma unroll
    for (int r = 0; r < 4; ++r) {
      const int px = ohl * 16 + quad * 4 + r;
#pragma unroll
      for (int nf = 0; nf < 2; ++nf) {
        const float vv = fmaxf(acc[mi][nf][r] * sc[nf] + bs[nf], 0.f);
        im[px * 40 + ((nf * 16 + l16) ^ (quad * 8))] = f2bf(vv);
      }
    }
  }
  __syncthreads();
  // cooperative store: 512 chunks of 16B; wave writes 1KB contiguous
#pragma unroll
  for (int i = 0; i < 2; ++i) {
    const int c = i * 256 + t;
    const int px = c >> 2, cg = c & 3;
    const int ohl = px >> 4, owl = px & 15;
    const uint4 v =
        *(const uint4*)(&im[px * 40 + ((cg ^ ((px >> 2) & 3)) * 8)]);
    *(uint4*)(y + (((size_t)n * 112 + oh0 + ohl) * 112 + ow0 + owl) * 32 +
              cg * 8) = v;
  }
}

// ---------------------------------------------------------------- conv2+conv3
// R25: R24 structure (setprio win: conv23 90.5->77us) + LINEAR FOLDED IN via
// last-block pattern: per-image counter; the 49th block of each image
// re-reads pooled coherently (atomicAdd(p,0)) and computes the 10 outputs.
// Saves the linear dispatch + launch gap. Union buffer, HS=2504 padding,
// (256,2) — all R21/R24-verified.
__global__ __launch_bounds__(256, 2) void conv23_fused(
    const unsigned short* __restrict__ act1,
    const unsigned short* __restrict__ bp2,
    const unsigned short* __restrict__ bp3,
    const float* __restrict__ g2, const float* __restrict__ b2,
    const float* __restrict__ m2, const float* __restrict__ v2,
    const float* __restrict__ g3, const float* __restrict__ b3,
    const float* __restrict__ m3, const float* __restrict__ v3,
    const float* __restrict__ red, float* __restrict__ pooled,
    int* __restrict__ cnt, const float* __restrict__ ql,
    const float* __restrict__ bl, float* __restrict__ out) {
  constexpr int HS = 2504;                 // hseg stride in shorts (pad +56)
  __shared__ unsigned short shbuf[8 * HS];  // 40064 B (union)
  __shared__ float pbuf[128];
  __shared__ int lastFlag;
  unsigned short* a1p = shbuf;  // 4*19*19*8 = 11552 shorts while live
  unsigned short* c2o = shbuf;  // 8*HS shorts after barrier
  const int t = threadIdx.x;
  const int img = blockIdx.y;
  const int ty = blockIdx.x / 7, tx = blockIdx.x % 7;
  const int wave = t >> 6, lane = t & 63, quad = lane >> 4, l16 = lane & 15;
  // conv2-output patch origin (abs 112-grid); conv3 input rows h0..h0+16
  const int h0 = ty * 16 - 1, w0 = tx * 16 - 1;

  // ---- Phase A: stage act1 rows h0-1..h0+17, cols w0-1..w0+17 (19x19)
  for (int c = t; c < 19 * 19 * 4; c += 256) {
    const int seg = c & 3, pix = c >> 2;
    const int ri = pix / 19, rj = pix % 19;
    const int ih = h0 - 1 + ri, iw = w0 - 1 + rj;
    uint4 v = make_uint4(0u, 0u, 0u, 0u);
    if ((unsigned)ih < 112u && (unsigned)iw < 112u)
      v = *(const uint4*)(act1 + (((size_t)img * 112 + ih) * 112 + iw) * 32 +
                          seg * 8);
    *(uint4*)(&a1p[((seg * 19 + ri) * 19 + rj) * 8]) = v;
  }

  // ---- Phase B geometry: wave w owns M-tiles w, w+4, ..., w+16
  int abase[5];
#pragma unroll
  for (int s = 0; s < 5; ++s) {
    const int mt = wave + s * 4;
    int apx = mt * 16 + l16;
    if (apx > 288) apx = 288;  // dummy lanes recompute px 288
    const int pi = apx / 17, pj = apx % 17;
    abase[s] = ((quad * 19 + pi) * 19 + pj) * 8;
  }
  floatx4 acc2[5][4];
#pragma unroll
  for (int s = 0; s < 5; ++s)
#pragma unroll
    for (int nf = 0; nf < 4; ++nf) acc2[s][nf] = (floatx4){0.f, 0.f, 0.f, 0.f};

  short8 bcur[4], bnxt[4];
#pragma unroll
  for (int nf = 0; nf < 4; ++nf)
    bcur[nf] = *(const short8*)(bp2 + ((size_t)quad * 64 + nf * 16 + l16) * 8);
  __syncthreads();

#pragma unroll
  for (int tap = 0; tap < 9; ++tap) {
    const int kh = tap / 3, kw = tap % 3;
    if (tap + 1 < 9) {
      const int kg = (tap + 1) * 4 + quad;
#pragma unroll
      for (int nf = 0; nf < 4; ++nf)
        bnxt[nf] =
            *(const short8*)(bp2 + ((size_t)kg * 64 + nf * 16 + l16) * 8);
    }
    const int toff = (kh * 19 + kw) * 8;
    __builtin_amdgcn_s_setprio(1);
#pragma unroll
    for (int s = 0; s < 5; ++s) {
      const short8 a = *(const short8*)(&a1p[abase[s] + toff]);
#pragma unroll
      for (int nf = 0; nf < 4; ++nf)
        acc2[s][nf] = __builtin_amdgcn_mfma_f32_16x16x32_bf16(
            a, bcur[nf], acc2[s][nf], 0, 0, 0);
    }
    __builtin_amdgcn_s_setprio(0);
#pragma unroll
    for (int nf = 0; nf < 4; ++nf) bcur[nf] = bnxt[nf];
  }
  __syncthreads();  // all a1p reads complete before c2o overwrites the union

  // ---- Phase B epilogue: BN2+ReLU -> c2o (parity-split), zero OOB px
  const float alpha2 = red[6] / fmaxf(red[5], 1.f);
  float sc[4], bs[4];
#pragma unroll
  for (int nf = 0; nf < 4; ++nf) {
    const int ch = nf * 16 + l16;
    const float inv = g2[ch] / sqrtf(v2[ch] + 1e-5f);
    sc[nf] = alpha2 * inv;
    bs[nf] = b2[ch] - m2[ch] * inv;
  }
  const int lo8 = l16 & 7, hs0 = l16 >> 3;  // hseg = nf*2 + hs0
#pragma unroll
  for (int s = 0; s < 5; ++s) {
    const int mt = wave + s * 4;
#pragma unroll
    for (int r = 0; r < 4; ++r) {
      const int px = mt * 16 + quad * 4 + r;  // C-row = quad*4+r (verified)
      if (px <= 288) {
        const int pi = px / 17, pj = px % 17;
        const int slot = (pj >> 1) + (pj & 1) * 9;
        const bool inb =
            ((unsigned)(h0 + pi) < 112u) && ((unsigned)(w0 + pj) < 112u);
#pragma unroll
        for (int nf = 0; nf < 4; ++nf) {
          const float vv =
              inb ? fmaxf(acc2[s][nf][r] * sc[nf] + bs[nf], 0.f) : 0.f;
          c2o[(nf * 2 + hs0) * HS + (pi * 18 + slot) * 8 + lo8] = f2bf(vv);
        }
      }
    }
  }
  __syncthreads();

  // ---- Phase C: conv3 (verified structure; half H -> hseg H*4+quad)
  int a3off[4];
#pragma unroll
  for (int mf = 0; mf < 4; ++mf) {
    const int px = mf * 16 + l16;
    a3off[mf] = quad * HS + (((px >> 3) * 2) * 18 + (px & 7)) * 8;
  }
  floatx4 acc3[4][2];
#pragma unroll
  for (int mf = 0; mf < 4; ++mf) {
    acc3[mf][0] = (floatx4){0.f, 0.f, 0.f, 0.f};
    acc3[mf][1] = (floatx4){0.f, 0.f, 0.f, 0.f};
  }
  short8 b3c0, b3c1, b3n0, b3n1;
  {
    const int kg = quad;  // u=0: tap=0, H=0
    b3c0 = *(const short8*)(bp3 + ((size_t)kg * 128 + wave * 32 + l16) * 8);
    b3c1 =
        *(const short8*)(bp3 + ((size_t)kg * 128 + wave * 32 + 16 + l16) * 8);
  }
#pragma unroll
  for (int u = 0; u < 18; ++u) {
    const int H = u / 9, tap = u % 9;
    const int kh = tap / 3, kw = tap % 3;
    if (u + 1 < 18) {
      const int H2 = (u + 1) / 9, tap2 = (u + 1) % 9;
      const int kg = tap2 * 8 + H2 * 4 + quad;
      b3n0 = *(const short8*)(bp3 + ((size_t)kg * 128 + wave * 32 + l16) * 8);
      b3n1 = *(const short8*)(bp3 +
                              ((size_t)kg * 128 + wave * 32 + 16 + l16) * 8);
    }
    // half H = 4 hsegs = 4*HS shorts
    const int toff = (kh * 18 + (kw >> 1) + (kw & 1) * 9) * 8 + H * 4 * HS;
    __builtin_amdgcn_s_setprio(1);
#pragma unroll
    for (int mf = 0; mf < 4; ++mf) {
      const short8 a = *(const short8*)(&c2o[a3off[mf] + toff]);
      acc3[mf][0] = __builtin_amdgcn_mfma_f32_16x16x32_bf16(
          a, b3c0, acc3[mf][0], 0, 0, 0);
      acc3[mf][1] = __builtin_amdgcn_mfma_f32_16x16x32_bf16(
          a, b3c1, acc3[mf][1], 0, 0, 0);
    }
    __builtin_amdgcn_s_setprio(0);
    b3c0 = b3n0; b3c1 = b3n1;
  }

  // ---- BN3 (inline fold) + ReLU + pool (waves own disjoint 32-ch slices)
  const float alpha3 = red[10] / fmaxf(red[9], 1.f);
#pragma unroll
  for (int nf = 0; nf < 2; ++nf) {
    const int ch = wave * 32 + nf * 16 + l16;
    const float inv = g3[ch] / sqrtf(v3[ch] + 1e-5f);
    const float scv = alpha3 * inv, bsv = b3[ch] - m3[ch] * inv;
    float s = 0.f;
#pragma unroll
    for (int mf = 0; mf < 4; ++mf)
#pragma unroll
      for (int rr = 0; rr < 4; ++rr)
        s += fmaxf(acc3[mf][nf][rr] * scv + bsv, 0.f);
    s += __shfl_xor(s, 16);
    s += __shfl_xor(s, 32);
    if (lane < 16) pbuf[ch] = s;
  }
  __syncthreads();
  if (t < 128) atomicAdd(&pooled[(size_t)img * 128 + t], pbuf[t]);

  // ---- last block of this image computes the linear layer
  __syncthreads();      // all this block's pooled atomics issued+drained
  __threadfence();      // device-scope release
  if (t == 0) lastFlag = (atomicAdd(&cnt[img], 1) == 48);
  __syncthreads();
  if (lastFlag) {
    __threadfence();    // acquire side
    if (t < 128)        // coherent re-read of the full pooled vector
      pbuf[t] = atomicAdd(&pooled[(size_t)img * 128 + t], 0.f);
    __syncthreads();
    if (t < 10) {
      const float* w = ql + (size_t)t * 128;
      float s = 0.f;
#pragma unroll 4
      for (int c2 = 0; c2 < 128; ++c2) s += pbuf[c2] * w[c2];
      const float alpha_l = red[14] / fmaxf(red[13], 1.f);
      out[(size_t)img * 10 + t] = s * (alpha_l / 3136.f) + bl[t];
    }
  }
}

// ---------------------------------------------------------------- launch
extern "C" void kernel_launch(void* const* d_in, const int* in_sizes, int n_in,
                              void* d_out, int out_size, void* d_ws,
                              size_t ws_size, hipStream_t stream) {
  const float* x  = (const float*)d_in[0];
  const float* w1 = (const float*)d_in[1];
  const float* g1 = (const float*)d_in[2];
  const float* b1 = (const float*)d_in[3];
  const float* m1 = (const float*)d_in[4];
  const float* v1 = (const float*)d_in[5];
  const float* w2 = (const float*)d_in[6];
  const float* g2 = (const float*)d_in[7];
  const float* b2 = (const float*)d_in[8];
  const float* m2 = (const float*)d_in[9];
  const float* v2 = (const float*)d_in[10];
  const float* w3 = (const float*)d_in[11];
  const float* g3 = (const float*)d_in[12];
  const float* b3 = (const float*)d_in[13];
  const float* m3 = (const float*)d_in[14];
  const float* v3 = (const float*)d_in[15];
  const float* wl = (const float*)d_in[16];
  const float* bl = (const float*)d_in[17];
  float* out = (float*)d_out;

  // ---- workspace layout (red/cnt/pooled/bp1 contiguous -> one memset)
  float* Wf = (float*)d_ws;
  float* red = Wf;                        // 16
  int* cnt = (int*)(red + 16);            // 64 (per-image block counters)
  float* pooled = red + 16 + 64;          // 8192
  float* bp1f = pooled + 8192;            // 512 floats = 1024 shorts (K32xN32)
  float* ql = bp1f + 512;                 // 1280
  unsigned short* bp1 = (unsigned short*)bp1f;
  unsigned short* Us = (unsigned short*)(ql + 1280);
  unsigned short* bp2 = Us;                 // 18432
  unsigned short* bp3 = bp2 + 18432;        // 73728
  unsigned short* act1 = bp3 + 73728;       // 64*12544*32 = 25690112
  // act2 eliminated (conv2+conv3 fused); total ~52 MB < ws_size

  // ---- prep: memset + 2 reduction/pack phases (BN fold inline) ----
  hipMemsetAsync(red, 0, (16 + 64 + 8192 + 512) * sizeof(float), stream);
  tern_phase1<<<dim3(288, 4), 256, 0, stream>>>(w1, w2, w3, wl, 864, 18432,
                                                73728, 1280, red);
  tern_phase2<<<dim3(288, 4), 256, 0, stream>>>(w1, w2, w3, wl, 864, 18432,
                                                73728, 1280, red, bp1, bp2,
                                                bp3, ql);

  // ---- network ----
  conv1_mfma<<<dim3(98, 64), 256, 0, stream>>>(x, bp1, g1, b1, m1, v1, red,
                                               act1);
  conv23_fused<<<dim3(49, 64), 256, 0, stream>>>(act1, bp2, bp3, g2, b2, m2,
                                                 v2, g3, b3, m3, v3, red,
                                                 pooled, cnt, ql, bl, out);
}

// Round 15
// 223.507 us; speedup vs baseline: 2.2094x; 2.2094x over previous
//
#include <hip/hip_runtime.h>
#include <cstddef>

typedef __attribute__((ext_vector_type(8))) short short8;
typedef __attribute__((ext_vector_type(4))) float floatx4;

// ---------------------------------------------------------------- bf16 utils
__device__ __forceinline__ unsigned short f2bf(float f) {
  union { float f; unsigned u; } v; v.f = f;
  const unsigned r = v.u + 0x7fffu + ((v.u >> 16) & 1u);  // RNE
  return (unsigned short)(r >> 16);
}

// ---------------------------------------------------------------- reductions
__device__ __forceinline__ float block_reduce_sum(float v, float* sm) {
#pragma unroll
  for (int off = 32; off > 0; off >>= 1) v += __shfl_down(v, off, 64);
  const int lane = threadIdx.x & 63, wid = threadIdx.x >> 6;
  __syncthreads();
  if (lane == 0) sm[wid] = v;
  __syncthreads();
  if (threadIdx.x == 0) {
    float t = 0.f;
    const int nw = (blockDim.x + 63) >> 6;
    for (int i = 0; i < nw; ++i) t += sm[i];
    sm[0] = t;
  }
  __syncthreads();
  return sm[0];
}

// ---------------------------------------------------------------- ternarize
// red[t*4+0]=sum|w|, red[t*4+1]=masked count, red[t*4+2]=masked sum|w|.
__device__ __forceinline__ void tsel(int t, const float* w0, const float* w1,
                                     const float* w2, const float* w3, int n0,
                                     int n1, int n2, int n3,
                                     const float*& w, int& n) {
  w = (t == 0) ? w0 : (t == 1) ? w1 : (t == 2) ? w2 : w3;
  n = (t == 0) ? n0 : (t == 1) ? n1 : (t == 2) ? n2 : n3;
}

__global__ __launch_bounds__(256) void tern_phase1(
    const float* w0, const float* w1, const float* w2, const float* w3,
    int n0, int n1, int n2, int n3, float* __restrict__ red) {
  __shared__ float sm[8];
  const float* w; int n;
  tsel(blockIdx.y, w0, w1, w2, w3, n0, n1, n2, n3, w, n);
  if ((int)blockIdx.x * 256 >= n) return;
  const int i = blockIdx.x * 256 + threadIdx.x;
  float s = (i < n) ? fabsf(w[i]) : 0.f;
  s = block_reduce_sum(s, sm);
  if (threadIdx.x == 0) atomicAdd(&red[blockIdx.y * 4 + 0], s);
}

// phase2: alpha sums AND all weight packing (reuses the loaded value).
// bp1: conv1 signs, K=32 (27 taps + 5 zeros from memset), k=ic*9+kh*3+kw,
//      dest ((k>>3)*32 + oc)*8 + (k&7)  -> lane B/A-frag = one 16B load
// bp2/bp3: bf16 sign, k=(kh*3+kw)*CIN+ic, dest ((k>>3)*COUT+n)*8+(k&7)
// ql: fp32 sign (alpha applied in linear via red)
__global__ __launch_bounds__(256) void tern_phase2(
    const float* w0, const float* w1, const float* w2, const float* w3,
    int n0, int n1, int n2, int n3, float* __restrict__ red,
    unsigned short* __restrict__ bp1, unsigned short* __restrict__ bp2,
    unsigned short* __restrict__ bp3, float* __restrict__ ql) {
  __shared__ float sm[8];
  const float* w; int n;
  const int by = blockIdx.y;
  tsel(by, w0, w1, w2, w3, n0, n1, n2, n3, w, n);
  if ((int)blockIdx.x * 256 >= n) return;
  const float delta = 0.7f * red[by * 4 + 0] / (float)n;
  const int i = blockIdx.x * 256 + threadIdx.x;
  float c = 0.f, a = 0.f;
  float wv = 0.f;
  if (i < n) {
    wv = w[i];
    const float av = fabsf(wv);
    if (av > delta) { c = 1.f; a = av; }
  }
  // ---- pack (independent of the reductions)
  if (i < n) {
    const float sgnf = (wv > delta) ? 1.f : (wv < -delta ? -1.f : 0.f);
    const unsigned short sgnb =
        (wv > delta) ? 0x3F80u : (wv < -delta ? 0xBF80u : 0u);
    if (by == 0) {
      const int k = i % 27, oc = i / 27;  // w1 OIHW flat: oc*27 + (ic*9+kh*3+kw)
      bp1[((size_t)(k >> 3) * 32 + oc) * 8 + (k & 7)] = sgnb;
    } else if (by == 1) {
      const int k = (i % 9) * 32 + (i % 288) / 9;
      bp2[((size_t)(k >> 3) * 64 + i / 288) * 8 + (k & 7)] = sgnb;
    } else if (by == 2) {
      const int k = (i % 9) * 64 + (i % 576) / 9;
      bp3[((size_t)(k >> 3) * 128 + i / 576) * 8 + (k & 7)] = sgnb;
    } else {
      ql[i] = sgnf;
    }
  }
  c = block_reduce_sum(c, sm);
  a = block_reduce_sum(a, sm);
  if (threadIdx.x == 0) {
    atomicAdd(&red[by * 4 + 1], c);
    atomicAdd(&red[by * 4 + 2], a);
  }
}

// ---------------------------------------------------------------- conv1 (MFMA)
// Implicit GEMM: block = 8x16 output px tile of one image (grid 98 x 64).
// R25's stage-once-bf16 KEPT (1683 f2bf instead of 4096; bit-identical).
__global__ __launch_bounds__(256) void conv1_mfma(
    const float* __restrict__ x, const unsigned short* __restrict__ bp1,
    const float* __restrict__ g1, const float* __restrict__ b1,
    const float* __restrict__ m1, const float* __restrict__ v1,
    const float* __restrict__ red, unsigned short* __restrict__ y) {
  __shared__ unsigned short xsb[3 * 17 * 33 + 1];  // 3368 B (bf16 patch)
  __shared__ unsigned short im[128 * 40];          // 10240 B
  const int n = blockIdx.y;
  const int oh0 = (blockIdx.x / 7) * 8, ow0 = (blockIdx.x % 7) * 16;
  const int t = threadIdx.x;
  const int wave = t >> 6, lane = t & 63, quad = lane >> 4, l16 = lane & 15;

  // ---- stage input patch as bf16 (zeros outside image); pad=1, stride=2
  const int ihb = oh0 * 2 - 1, iwb = ow0 * 2 - 1;
  for (int i = t; i < 1683; i += 256) {
    const int ic = i / 561, r2 = i % 561;
    const int pr = r2 / 33, pc = r2 % 33;
    const int ih = ihb + pr, iw = iwb + pc;
    float v = 0.f;
    if ((unsigned)ih < 224u && (unsigned)iw < 224u)
      v = x[((size_t)n * 3 + ic) * 50176 + (size_t)ih * 224 + iw];
    xsb[i] = f2bf(v);
  }
  __syncthreads();

  // ---- im2col: chunk = (px, seg) -> 8 bf16 k-values, one 16B write
#pragma unroll
  for (int cc = 0; cc < 2; ++cc) {
    const int c = cc * 256 + t;
    const int px = c >> 2, seg = c & 3;
    const int ohl = px >> 4, owl = px & 15;
    unsigned u[4];
#pragma unroll
    for (int jj = 0; jj < 4; ++jj) {
      unsigned short lo = 0, hi = 0;
      const int k0 = seg * 8 + 2 * jj, k1 = k0 + 1;
      if (k0 < 27) {
        const int ic = k0 / 9, tp = k0 % 9;
        lo = xsb[(ic * 17 + ohl * 2 + tp / 3) * 33 + owl * 2 + tp % 3];
      }
      if (k1 < 27) {
        const int ic = k1 / 9, tp = k1 % 9;
        hi = xsb[(ic * 17 + ohl * 2 + tp / 3) * 33 + owl * 2 + tp % 3];
      }
      u[jj] = (unsigned)lo | ((unsigned)hi << 16);
    }
    *(uint4*)(&im[px * 40 + seg * 8]) = make_uint4(u[0], u[1], u[2], u[3]);
  }

  // ---- B fragments (k = quad*8+j, n = nf*16+l16)
  short8 bfr[2];
#pragma unroll
  for (int nf = 0; nf < 2; ++nf)
    bfr[nf] = *(const short8*)(bp1 + ((size_t)quad * 32 + nf * 16 + l16) * 8);

  floatx4 acc[2][2];
#pragma unroll
  for (int mi = 0; mi < 2; ++mi) {
    acc[mi][0] = (floatx4){0.f, 0.f, 0.f, 0.f};
    acc[mi][1] = (floatx4){0.f, 0.f, 0.f, 0.f};
  }
  __syncthreads();

#pragma unroll
  for (int mi = 0; mi < 2; ++mi) {
    const int pxb = (wave * 2 + mi) * 16;
    const short8 a = *(const short8*)(&im[(pxb + l16) * 40 + quad * 8]);
#pragma unroll
    for (int nf = 0; nf < 2; ++nf)
      acc[mi][nf] = __builtin_amdgcn_mfma_f32_16x16x32_bf16(
          a, bfr[nf], acc[mi][nf], 0, 0, 0);
  }

  // ---- epilogue: BN1 (inline fold) + ReLU -> LDS (reuse im) -> coalesced
  const float alpha1 = red[2] / fmaxf(red[1], 1.f);
  float sc[2], bs[2];
#pragma unroll
  for (int nf = 0; nf < 2; ++nf) {
    const int ch = nf * 16 + l16;
    const float inv = g1[ch] / sqrtf(v1[ch] + 1e-5f);
    sc[nf] = alpha1 * inv;
    bs[nf] = b1[ch] - m1[ch] * inv;
  }
  __syncthreads();  // all waves' A-frag reads of im complete
  // st layout: [px][40 ushorts] (32 ch + 8 pad), ch XOR-swizzled by quad
#pragma unroll
  for (int mi = 0; mi < 2; ++mi) {
    const int ohl = wave * 2 + mi;
#pragma unroll
    for (int r = 0; r < 4; ++r) {
      const int px = ohl * 16 + quad * 4 + r;
#pragma unroll
      for (int nf = 0; nf < 2; ++nf) {
        const float vv = fmaxf(acc[mi][nf][r] * sc[nf] + bs[nf], 0.f);
        im[px * 40 + ((nf * 16 + l16) ^ (quad * 8))] = f2bf(vv);
      }
    }
  }
  __syncthreads();
  // cooperative store: 512 chunks of 16B; wave writes 1KB contiguous
#pragma unroll
  for (int i = 0; i < 2; ++i) {
    const int c = i * 256 + t;
    const int px = c >> 2, cg = c & 3;
    const int ohl = px >> 4, owl = px & 15;
    const uint4 v =
        *(const uint4*)(&im[px * 40 + ((cg ^ ((px >> 2) & 3)) * 8)]);
    *(uint4*)(y + (((size_t)n * 112 + oh0 + ohl) * 112 + ow0 + owl) * 32 +
              cg * 8) = v;
  }
}

// ---------------------------------------------------------------- conv2+conv3
// R26: EXACT R24 body (77us verified). R25's linear fold-in REVERTED:
// its 2 device-scope __threadfence() per block x 3136 blocks serialized L2
// across XCDs (conv23 77->360us, MfmaUtil 36->7%). Linear is a separate
// 3us kernel again. Union buffer, HS=2504 padding, setprio, (256,2).
__global__ __launch_bounds__(256, 2) void conv23_fused(
    const unsigned short* __restrict__ act1,
    const unsigned short* __restrict__ bp2,
    const unsigned short* __restrict__ bp3,
    const float* __restrict__ g2, const float* __restrict__ b2,
    const float* __restrict__ m2, const float* __restrict__ v2,
    const float* __restrict__ g3, const float* __restrict__ b3,
    const float* __restrict__ m3, const float* __restrict__ v3,
    const float* __restrict__ red, float* __restrict__ pooled) {
  constexpr int HS = 2504;                 // hseg stride in shorts (pad +56)
  __shared__ unsigned short shbuf[8 * HS];  // 40064 B (union)
  __shared__ float pbuf[128];
  unsigned short* a1p = shbuf;  // 4*19*19*8 = 11552 shorts while live
  unsigned short* c2o = shbuf;  // 8*HS shorts after barrier
  const int t = threadIdx.x;
  const int img = blockIdx.y;
  const int ty = blockIdx.x / 7, tx = blockIdx.x % 7;
  const int wave = t >> 6, lane = t & 63, quad = lane >> 4, l16 = lane & 15;
  // conv2-output patch origin (abs 112-grid); conv3 input rows h0..h0+16
  const int h0 = ty * 16 - 1, w0 = tx * 16 - 1;

  // ---- Phase A: stage act1 rows h0-1..h0+17, cols w0-1..w0+17 (19x19)
  for (int c = t; c < 19 * 19 * 4; c += 256) {
    const int seg = c & 3, pix = c >> 2;
    const int ri = pix / 19, rj = pix % 19;
    const int ih = h0 - 1 + ri, iw = w0 - 1 + rj;
    uint4 v = make_uint4(0u, 0u, 0u, 0u);
    if ((unsigned)ih < 112u && (unsigned)iw < 112u)
      v = *(const uint4*)(act1 + (((size_t)img * 112 + ih) * 112 + iw) * 32 +
                          seg * 8);
    *(uint4*)(&a1p[((seg * 19 + ri) * 19 + rj) * 8]) = v;
  }

  // ---- Phase B geometry: wave w owns M-tiles w, w+4, ..., w+16
  int abase[5];
#pragma unroll
  for (int s = 0; s < 5; ++s) {
    const int mt = wave + s * 4;
    int apx = mt * 16 + l16;
    if (apx > 288) apx = 288;  // dummy lanes recompute px 288
    const int pi = apx / 17, pj = apx % 17;
    abase[s] = ((quad * 19 + pi) * 19 + pj) * 8;
  }
  floatx4 acc2[5][4];
#pragma unroll
  for (int s = 0; s < 5; ++s)
#pragma unroll
    for (int nf = 0; nf < 4; ++nf) acc2[s][nf] = (floatx4){0.f, 0.f, 0.f, 0.f};

  short8 bcur[4], bnxt[4];
#pragma unroll
  for (int nf = 0; nf < 4; ++nf)
    bcur[nf] = *(const short8*)(bp2 + ((size_t)quad * 64 + nf * 16 + l16) * 8);
  __syncthreads();

#pragma unroll
  for (int tap = 0; tap < 9; ++tap) {
    const int kh = tap / 3, kw = tap % 3;
    if (tap + 1 < 9) {
      const int kg = (tap + 1) * 4 + quad;
#pragma unroll
      for (int nf = 0; nf < 4; ++nf)
        bnxt[nf] =
            *(const short8*)(bp2 + ((size_t)kg * 64 + nf * 16 + l16) * 8);
    }
    const int toff = (kh * 19 + kw) * 8;
    __builtin_amdgcn_s_setprio(1);
#pragma unroll
    for (int s = 0; s < 5; ++s) {
      const short8 a = *(const short8*)(&a1p[abase[s] + toff]);
#pragma unroll
      for (int nf = 0; nf < 4; ++nf)
        acc2[s][nf] = __builtin_amdgcn_mfma_f32_16x16x32_bf16(
            a, bcur[nf], acc2[s][nf], 0, 0, 0);
    }
    __builtin_amdgcn_s_setprio(0);
#pragma unroll
    for (int nf = 0; nf < 4; ++nf) bcur[nf] = bnxt[nf];
  }
  __syncthreads();  // all a1p reads complete before c2o overwrites the union

  // ---- Phase B epilogue: BN2+ReLU -> c2o (parity-split), zero OOB px
  const float alpha2 = red[6] / fmaxf(red[5], 1.f);
  float sc[4], bs[4];
#pragma unroll
  for (int nf = 0; nf < 4; ++nf) {
    const int ch = nf * 16 + l16;
    const float inv = g2[ch] / sqrtf(v2[ch] + 1e-5f);
    sc[nf] = alpha2 * inv;
    bs[nf] = b2[ch] - m2[ch] * inv;
  }
  const int lo8 = l16 & 7, hs0 = l16 >> 3;  // hseg = nf*2 + hs0
#pragma unroll
  for (int s = 0; s < 5; ++s) {
    const int mt = wave + s * 4;
#pragma unroll
    for (int r = 0; r < 4; ++r) {
      const int px = mt * 16 + quad * 4 + r;  // C-row = quad*4+r (verified)
      if (px <= 288) {
        const int pi = px / 17, pj = px % 17;
        const int slot = (pj >> 1) + (pj & 1) * 9;
        const bool inb =
            ((unsigned)(h0 + pi) < 112u) && ((unsigned)(w0 + pj) < 112u);
#pragma unroll
        for (int nf = 0; nf < 4; ++nf) {
          const float vv =
              inb ? fmaxf(acc2[s][nf][r] * sc[nf] + bs[nf], 0.f) : 0.f;
          c2o[(nf * 2 + hs0) * HS + (pi * 18 + slot) * 8 + lo8] = f2bf(vv);
        }
      }
    }
  }
  __syncthreads();

  // ---- Phase C: conv3 (verified structure; half H -> hseg H*4+quad)
  int a3off[4];
#pragma unroll
  for (int mf = 0; mf < 4; ++mf) {
    const int px = mf * 16 + l16;
    a3off[mf] = quad * HS + (((px >> 3) * 2) * 18 + (px & 7)) * 8;
  }
  floatx4 acc3[4][2];
#pragma unroll
  for (int mf = 0; mf < 4; ++mf) {
    acc3[mf][0] = (floatx4){0.f, 0.f, 0.f, 0.f};
    acc3[mf][1] = (floatx4){0.f, 0.f, 0.f, 0.f};
  }
  short8 b3c0, b3c1, b3n0, b3n1;
  {
    const int kg = quad;  // u=0: tap=0, H=0
    b3c0 = *(const short8*)(bp3 + ((size_t)kg * 128 + wave * 32 + l16) * 8);
    b3c1 =
        *(const short8*)(bp3 + ((size_t)kg * 128 + wave * 32 + 16 + l16) * 8);
  }
#pragma unroll
  for (int u = 0; u < 18; ++u) {
    const int H = u / 9, tap = u % 9;
    const int kh = tap / 3, kw = tap % 3;
    if (u + 1 < 18) {
      const int H2 = (u + 1) / 9, tap2 = (u + 1) % 9;
      const int kg = tap2 * 8 + H2 * 4 + quad;
      b3n0 = *(const short8*)(bp3 + ((size_t)kg * 128 + wave * 32 + l16) * 8);
      b3n1 = *(const short8*)(bp3 +
                              ((size_t)kg * 128 + wave * 32 + 16 + l16) * 8);
    }
    // half H = 4 hsegs = 4*HS shorts
    const int toff = (kh * 18 + (kw >> 1) + (kw & 1) * 9) * 8 + H * 4 * HS;
    __builtin_amdgcn_s_setprio(1);
#pragma unroll
    for (int mf = 0; mf < 4; ++mf) {
      const short8 a = *(const short8*)(&c2o[a3off[mf] + toff]);
      acc3[mf][0] = __builtin_amdgcn_mfma_f32_16x16x32_bf16(
          a, b3c0, acc3[mf][0], 0, 0, 0);
      acc3[mf][1] = __builtin_amdgcn_mfma_f32_16x16x32_bf16(
          a, b3c1, acc3[mf][1], 0, 0, 0);
    }
    __builtin_amdgcn_s_setprio(0);
    b3c0 = b3n0; b3c1 = b3n1;
  }

  // ---- BN3 (inline fold) + ReLU + pool (waves own disjoint 32-ch slices)
  const float alpha3 = red[10] / fmaxf(red[9], 1.f);
#pragma unroll
  for (int nf = 0; nf < 2; ++nf) {
    const int ch = wave * 32 + nf * 16 + l16;
    const float inv = g3[ch] / sqrtf(v3[ch] + 1e-5f);
    const float scv = alpha3 * inv, bsv = b3[ch] - m3[ch] * inv;
    float s = 0.f;
#pragma unroll
    for (int mf = 0; mf < 4; ++mf)
#pragma unroll
      for (int rr = 0; rr < 4; ++rr)
        s += fmaxf(acc3[mf][nf][rr] * scv + bsv, 0.f);
    s += __shfl_xor(s, 16);
    s += __shfl_xor(s, 32);
    if (lane < 16) pbuf[ch] = s;
  }
  __syncthreads();
  if (t < 128) atomicAdd(&pooled[(size_t)img * 128 + t], pbuf[t]);
}

// ---------------------------------------------------------------- linear
// pooled holds SUMS over 3136 px; ql holds signs; alpha_l from red.
__global__ void linear_kernel(const float* __restrict__ pooled,
                              const float* __restrict__ ql,
                              const float* __restrict__ bl,
                              const float* __restrict__ red,
                              float* __restrict__ out) {
  const int idx = blockIdx.x * blockDim.x + threadIdx.x;
  if (idx >= 64 * 10) return;
  const int n = idx / 10, o = idx % 10;
  const float* p = pooled + (size_t)n * 128;
  const float* w = ql + (size_t)o * 128;
  float s = 0.f;
#pragma unroll 4
  for (int c = 0; c < 128; ++c) s += p[c] * w[c];
  const float alpha_l = red[14] / fmaxf(red[13], 1.f);
  out[idx] = s * (alpha_l / 3136.f) + bl[o];
}

// ---------------------------------------------------------------- launch
extern "C" void kernel_launch(void* const* d_in, const int* in_sizes, int n_in,
                              void* d_out, int out_size, void* d_ws,
                              size_t ws_size, hipStream_t stream) {
  const float* x  = (const float*)d_in[0];
  const float* w1 = (const float*)d_in[1];
  const float* g1 = (const float*)d_in[2];
  const float* b1 = (const float*)d_in[3];
  const float* m1 = (const float*)d_in[4];
  const float* v1 = (const float*)d_in[5];
  const float* w2 = (const float*)d_in[6];
  const float* g2 = (const float*)d_in[7];
  const float* b2 = (const float*)d_in[8];
  const float* m2 = (const float*)d_in[9];
  const float* v2 = (const float*)d_in[10];
  const float* w3 = (const float*)d_in[11];
  const float* g3 = (const float*)d_in[12];
  const float* b3 = (const float*)d_in[13];
  const float* m3 = (const float*)d_in[14];
  const float* v3 = (const float*)d_in[15];
  const float* wl = (const float*)d_in[16];
  const float* bl = (const float*)d_in[17];
  float* out = (float*)d_out;

  // ---- workspace layout (red/pooled/bp1 contiguous -> one zeroing memset)
  float* Wf = (float*)d_ws;
  float* red = Wf;                        // 16
  float* pooled = red + 16;               // 8192
  float* bp1f = pooled + 8192;            // 512 floats = 1024 shorts (K32xN32)
  float* ql = bp1f + 512;                 // 1280
  unsigned short* bp1 = (unsigned short*)bp1f;
  unsigned short* Us = (unsigned short*)(ql + 1280);
  unsigned short* bp2 = Us;                 // 18432
  unsigned short* bp3 = bp2 + 18432;        // 73728
  unsigned short* act1 = bp3 + 73728;       // 64*12544*32 = 25690112
  // act2 eliminated (conv2+conv3 fused); total ~52 MB < ws_size

  // ---- prep: memset + 2 reduction/pack phases (BN fold inline) ----
  hipMemsetAsync(red, 0, (16 + 8192 + 512) * sizeof(float), stream);
  tern_phase1<<<dim3(288, 4), 256, 0, stream>>>(w1, w2, w3, wl, 864, 18432,
                                                73728, 1280, red);
  tern_phase2<<<dim3(288, 4), 256, 0, stream>>>(w1, w2, w3, wl, 864, 18432,
                                                73728, 1280, red, bp1, bp2,
                                                bp3, ql);

  // ---- network ----
  conv1_mfma<<<dim3(98, 64), 256, 0, stream>>>(x, bp1, g1, b1, m1, v1, red,
                                               act1);
  conv23_fused<<<dim3(49, 64), 256, 0, stream>>>(act1, bp2, bp3, g2, b2, m2,
                                                 v2, g3, b3, m3, v3, red,
                                                 pooled);
  linear_kernel<<<3, 256, 0, stream>>>(pooled, ql, bl, red, out);
}

// Round 16
// 220.837 us; speedup vs baseline: 2.2361x; 1.0121x over previous
//
#include <hip/hip_runtime.h>
#include <cstddef>

typedef __attribute__((ext_vector_type(8))) short short8;
typedef __attribute__((ext_vector_type(4))) float floatx4;

// ---------------------------------------------------------------- bf16 utils
__device__ __forceinline__ unsigned short f2bf(float f) {
  union { float f; unsigned u; } v; v.f = f;
  const unsigned r = v.u + 0x7fffu + ((v.u >> 16) & 1u);  // RNE
  return (unsigned short)(r >> 16);
}

// ---------------------------------------------------------------- reductions
__device__ __forceinline__ float block_reduce_sum(float v, float* sm) {
#pragma unroll
  for (int off = 32; off > 0; off >>= 1) v += __shfl_down(v, off, 64);
  const int lane = threadIdx.x & 63, wid = threadIdx.x >> 6;
  __syncthreads();
  if (lane == 0) sm[wid] = v;
  __syncthreads();
  if (threadIdx.x == 0) {
    float t = 0.f;
    const int nw = (blockDim.x + 63) >> 6;
    for (int i = 0; i < nw; ++i) t += sm[i];
    sm[0] = t;
  }
  __syncthreads();
  return sm[0];
}

// ---------------------------------------------------------------- ternarize
// red[t*4+0]=sum|w|, red[t*4+1]=masked count, red[t*4+2]=masked sum|w|.
__device__ __forceinline__ void tsel(int t, const float* w0, const float* w1,
                                     const float* w2, const float* w3, int n0,
                                     int n1, int n2, int n3,
                                     const float*& w, int& n) {
  w = (t == 0) ? w0 : (t == 1) ? w1 : (t == 2) ? w2 : w3;
  n = (t == 0) ? n0 : (t == 1) ? n1 : (t == 2) ? n2 : n3;
}

__global__ __launch_bounds__(256) void tern_phase1(
    const float* w0, const float* w1, const float* w2, const float* w3,
    int n0, int n1, int n2, int n3, float* __restrict__ red) {
  __shared__ float sm[8];
  const float* w; int n;
  tsel(blockIdx.y, w0, w1, w2, w3, n0, n1, n2, n3, w, n);
  if ((int)blockIdx.x * 256 >= n) return;
  const int i = blockIdx.x * 256 + threadIdx.x;
  float s = (i < n) ? fabsf(w[i]) : 0.f;
  s = block_reduce_sum(s, sm);
  if (threadIdx.x == 0) atomicAdd(&red[blockIdx.y * 4 + 0], s);
}

// phase2: alpha sums AND all weight packing (reuses the loaded value).
// bp1: conv1 signs, K=32 (27 taps + 5 zeros from memset), k=ic*9+kh*3+kw,
//      dest ((k>>3)*32 + oc)*8 + (k&7)  -> lane B/A-frag = one 16B load
// bp2/bp3: bf16 sign, k=(kh*3+kw)*CIN+ic, dest ((k>>3)*COUT+n)*8+(k&7)
// ql: fp32 sign (alpha applied in linear via red)
__global__ __launch_bounds__(256) void tern_phase2(
    const float* w0, const float* w1, const float* w2, const float* w3,
    int n0, int n1, int n2, int n3, float* __restrict__ red,
    unsigned short* __restrict__ bp1, unsigned short* __restrict__ bp2,
    unsigned short* __restrict__ bp3, float* __restrict__ ql) {
  __shared__ float sm[8];
  const float* w; int n;
  const int by = blockIdx.y;
  tsel(by, w0, w1, w2, w3, n0, n1, n2, n3, w, n);
  if ((int)blockIdx.x * 256 >= n) return;
  const float delta = 0.7f * red[by * 4 + 0] / (float)n;
  const int i = blockIdx.x * 256 + threadIdx.x;
  float c = 0.f, a = 0.f;
  float wv = 0.f;
  if (i < n) {
    wv = w[i];
    const float av = fabsf(wv);
    if (av > delta) { c = 1.f; a = av; }
  }
  // ---- pack (independent of the reductions)
  if (i < n) {
    const float sgnf = (wv > delta) ? 1.f : (wv < -delta ? -1.f : 0.f);
    const unsigned short sgnb =
        (wv > delta) ? 0x3F80u : (wv < -delta ? 0xBF80u : 0u);
    if (by == 0) {
      const int k = i % 27, oc = i / 27;  // w1 OIHW flat: oc*27 + (ic*9+kh*3+kw)
      bp1[((size_t)(k >> 3) * 32 + oc) * 8 + (k & 7)] = sgnb;
    } else if (by == 1) {
      const int k = (i % 9) * 32 + (i % 288) / 9;
      bp2[((size_t)(k >> 3) * 64 + i / 288) * 8 + (k & 7)] = sgnb;
    } else if (by == 2) {
      const int k = (i % 9) * 64 + (i % 576) / 9;
      bp3[((size_t)(k >> 3) * 128 + i / 576) * 8 + (k & 7)] = sgnb;
    } else {
      ql[i] = sgnf;
    }
  }
  c = block_reduce_sum(c, sm);
  a = block_reduce_sum(a, sm);
  if (threadIdx.x == 0) {
    atomicAdd(&red[by * 4 + 1], c);
    atomicAdd(&red[by * 4 + 2], a);
  }
}

// ---------------------------------------------------------------- conv1 (MFMA)
// Implicit GEMM: block = 8x16 output px tile of one image (grid 98 x 64).
// R27: A-fragments built DIRECTLY from xsb. Each (px, k-octet) of the
// im2col matrix is consumed by exactly one lane (px=pxb+l16 -> owl=l16,
// ohl=wave*2+mi, seg=quad is a bijection), so the cooperative im2col phase
// (LDS round-trip through `im`) + one barrier were pure overhead. Identical
// math; stride-2 u16 xsb reads are <=2-way bank alias (free). `im` now only
// the store-transpose buffer. Barriers 3->2.
__global__ __launch_bounds__(256) void conv1_mfma(
    const float* __restrict__ x, const unsigned short* __restrict__ bp1,
    const float* __restrict__ g1, const float* __restrict__ b1,
    const float* __restrict__ m1, const float* __restrict__ v1,
    const float* __restrict__ red, unsigned short* __restrict__ y) {
  __shared__ unsigned short xsb[3 * 17 * 33 + 1];  // 3368 B (bf16 patch)
  __shared__ unsigned short im[128 * 40];          // 10240 B (store tile)
  const int n = blockIdx.y;
  const int oh0 = (blockIdx.x / 7) * 8, ow0 = (blockIdx.x % 7) * 16;
  const int t = threadIdx.x;
  const int wave = t >> 6, lane = t & 63, quad = lane >> 4, l16 = lane & 15;

  // ---- stage input patch as bf16 (zeros outside image); pad=1, stride=2
  const int ihb = oh0 * 2 - 1, iwb = ow0 * 2 - 1;
  for (int i = t; i < 1683; i += 256) {
    const int ic = i / 561, r2 = i % 561;
    const int pr = r2 / 33, pc = r2 % 33;
    const int ih = ihb + pr, iw = iwb + pc;
    float v = 0.f;
    if ((unsigned)ih < 224u && (unsigned)iw < 224u)
      v = x[((size_t)n * 3 + ic) * 50176 + (size_t)ih * 224 + iw];
    xsb[i] = f2bf(v);
  }

  // ---- B fragments (k = quad*8+j, n = nf*16+l16)
  short8 bfr[2];
#pragma unroll
  for (int nf = 0; nf < 2; ++nf)
    bfr[nf] = *(const short8*)(bp1 + ((size_t)quad * 32 + nf * 16 + l16) * 8);

  floatx4 acc[2][2];
#pragma unroll
  for (int mi = 0; mi < 2; ++mi) {
    acc[mi][0] = (floatx4){0.f, 0.f, 0.f, 0.f};
    acc[mi][1] = (floatx4){0.f, 0.f, 0.f, 0.f};
  }
  __syncthreads();

  // ---- A-frags direct from xsb (owl = l16, ohl = wave*2+mi, k = quad*8+j)
#pragma unroll
  for (int mi = 0; mi < 2; ++mi) {
    const int ohl = wave * 2 + mi;
    union { unsigned u[4]; short8 s; } av;
#pragma unroll
    for (int jj = 0; jj < 4; ++jj) {
      unsigned short lo = 0, hi = 0;
      const int k0 = quad * 8 + 2 * jj, k1 = k0 + 1;
      if (k0 < 27) {
        const int ic = k0 / 9, tp = k0 % 9;
        lo = xsb[(ic * 17 + ohl * 2 + tp / 3) * 33 + l16 * 2 + tp % 3];
      }
      if (k1 < 27) {
        const int ic = k1 / 9, tp = k1 % 9;
        hi = xsb[(ic * 17 + ohl * 2 + tp / 3) * 33 + l16 * 2 + tp % 3];
      }
      av.u[jj] = (unsigned)lo | ((unsigned)hi << 16);
    }
#pragma unroll
    for (int nf = 0; nf < 2; ++nf)
      acc[mi][nf] = __builtin_amdgcn_mfma_f32_16x16x32_bf16(
          av.s, bfr[nf], acc[mi][nf], 0, 0, 0);
  }

  // ---- epilogue: BN1 (inline fold) + ReLU -> LDS (im) -> coalesced store
  const float alpha1 = red[2] / fmaxf(red[1], 1.f);
  float sc[2], bs[2];
#pragma unroll
  for (int nf = 0; nf < 2; ++nf) {
    const int ch = nf * 16 + l16;
    const float inv = g1[ch] / sqrtf(v1[ch] + 1e-5f);
    sc[nf] = alpha1 * inv;
    bs[nf] = b1[ch] - m1[ch] * inv;
  }
  // st layout: [px][40 ushorts] (32 ch + 8 pad), ch XOR-swizzled by quad
#pragma unroll
  for (int mi = 0; mi < 2; ++mi) {
    const int ohl = wave * 2 + mi;
#pragma unroll
    for (int r = 0; r < 4; ++r) {
      const int px = ohl * 16 + quad * 4 + r;
#pragma unroll
      for (int nf = 0; nf < 2; ++nf) {
        const float vv = fmaxf(acc[mi][nf][r] * sc[nf] + bs[nf], 0.f);
        im[px * 40 + ((nf * 16 + l16) ^ (quad * 8))] = f2bf(vv);
      }
    }
  }
  __syncthreads();
  // cooperative store: 512 chunks of 16B; wave writes 1KB contiguous
#pragma unroll
  for (int i = 0; i < 2; ++i) {
    const int c = i * 256 + t;
    const int px = c >> 2, cg = c & 3;
    const int ohl = px >> 4, owl = px & 15;
    const uint4 v =
        *(const uint4*)(&im[px * 40 + ((cg ^ ((px >> 2) & 3)) * 8)]);
    *(uint4*)(y + (((size_t)n * 112 + oh0 + ohl) * 112 + ow0 + owl) * 32 +
              cg * 8) = v;
  }
}

// ---------------------------------------------------------------- conv2+conv3
// R24/R26 body (77us verified): union buffer (a1p while live, c2o after
// barrier), HS=2504 bank padding, setprio around MFMA clusters, (256,2).
__global__ __launch_bounds__(256, 2) void conv23_fused(
    const unsigned short* __restrict__ act1,
    const unsigned short* __restrict__ bp2,
    const unsigned short* __restrict__ bp3,
    const float* __restrict__ g2, const float* __restrict__ b2,
    const float* __restrict__ m2, const float* __restrict__ v2,
    const float* __restrict__ g3, const float* __restrict__ b3,
    const float* __restrict__ m3, const float* __restrict__ v3,
    const float* __restrict__ red, float* __restrict__ pooled) {
  constexpr int HS = 2504;                 // hseg stride in shorts (pad +56)
  __shared__ unsigned short shbuf[8 * HS];  // 40064 B (union)
  __shared__ float pbuf[128];
  unsigned short* a1p = shbuf;  // 4*19*19*8 = 11552 shorts while live
  unsigned short* c2o = shbuf;  // 8*HS shorts after barrier
  const int t = threadIdx.x;
  const int img = blockIdx.y;
  const int ty = blockIdx.x / 7, tx = blockIdx.x % 7;
  const int wave = t >> 6, lane = t & 63, quad = lane >> 4, l16 = lane & 15;
  // conv2-output patch origin (abs 112-grid); conv3 input rows h0..h0+16
  const int h0 = ty * 16 - 1, w0 = tx * 16 - 1;

  // ---- Phase A: stage act1 rows h0-1..h0+17, cols w0-1..w0+17 (19x19)
  for (int c = t; c < 19 * 19 * 4; c += 256) {
    const int seg = c & 3, pix = c >> 2;
    const int ri = pix / 19, rj = pix % 19;
    const int ih = h0 - 1 + ri, iw = w0 - 1 + rj;
    uint4 v = make_uint4(0u, 0u, 0u, 0u);
    if ((unsigned)ih < 112u && (unsigned)iw < 112u)
      v = *(const uint4*)(act1 + (((size_t)img * 112 + ih) * 112 + iw) * 32 +
                          seg * 8);
    *(uint4*)(&a1p[((seg * 19 + ri) * 19 + rj) * 8]) = v;
  }

  // ---- Phase B geometry: wave w owns M-tiles w, w+4, ..., w+16
  int abase[5];
#pragma unroll
  for (int s = 0; s < 5; ++s) {
    const int mt = wave + s * 4;
    int apx = mt * 16 + l16;
    if (apx > 288) apx = 288;  // dummy lanes recompute px 288
    const int pi = apx / 17, pj = apx % 17;
    abase[s] = ((quad * 19 + pi) * 19 + pj) * 8;
  }
  floatx4 acc2[5][4];
#pragma unroll
  for (int s = 0; s < 5; ++s)
#pragma unroll
    for (int nf = 0; nf < 4; ++nf) acc2[s][nf] = (floatx4){0.f, 0.f, 0.f, 0.f};

  short8 bcur[4], bnxt[4];
#pragma unroll
  for (int nf = 0; nf < 4; ++nf)
    bcur[nf] = *(const short8*)(bp2 + ((size_t)quad * 64 + nf * 16 + l16) * 8);
  __syncthreads();

#pragma unroll
  for (int tap = 0; tap < 9; ++tap) {
    const int kh = tap / 3, kw = tap % 3;
    if (tap + 1 < 9) {
      const int kg = (tap + 1) * 4 + quad;
#pragma unroll
      for (int nf = 0; nf < 4; ++nf)
        bnxt[nf] =
            *(const short8*)(bp2 + ((size_t)kg * 64 + nf * 16 + l16) * 8);
    }
    const int toff = (kh * 19 + kw) * 8;
    __builtin_amdgcn_s_setprio(1);
#pragma unroll
    for (int s = 0; s < 5; ++s) {
      const short8 a = *(const short8*)(&a1p[abase[s] + toff]);
#pragma unroll
      for (int nf = 0; nf < 4; ++nf)
        acc2[s][nf] = __builtin_amdgcn_mfma_f32_16x16x32_bf16(
            a, bcur[nf], acc2[s][nf], 0, 0, 0);
    }
    __builtin_amdgcn_s_setprio(0);
#pragma unroll
    for (int nf = 0; nf < 4; ++nf) bcur[nf] = bnxt[nf];
  }
  __syncthreads();  // all a1p reads complete before c2o overwrites the union

  // ---- Phase B epilogue: BN2+ReLU -> c2o (parity-split), zero OOB px
  const float alpha2 = red[6] / fmaxf(red[5], 1.f);
  float sc[4], bs[4];
#pragma unroll
  for (int nf = 0; nf < 4; ++nf) {
    const int ch = nf * 16 + l16;
    const float inv = g2[ch] / sqrtf(v2[ch] + 1e-5f);
    sc[nf] = alpha2 * inv;
    bs[nf] = b2[ch] - m2[ch] * inv;
  }
  const int lo8 = l16 & 7, hs0 = l16 >> 3;  // hseg = nf*2 + hs0
#pragma unroll
  for (int s = 0; s < 5; ++s) {
    const int mt = wave + s * 4;
#pragma unroll
    for (int r = 0; r < 4; ++r) {
      const int px = mt * 16 + quad * 4 + r;  // C-row = quad*4+r (verified)
      if (px <= 288) {
        const int pi = px / 17, pj = px % 17;
        const int slot = (pj >> 1) + (pj & 1) * 9;
        const bool inb =
            ((unsigned)(h0 + pi) < 112u) && ((unsigned)(w0 + pj) < 112u);
#pragma unroll
        for (int nf = 0; nf < 4; ++nf) {
          const float vv =
              inb ? fmaxf(acc2[s][nf][r] * sc[nf] + bs[nf], 0.f) : 0.f;
          c2o[(nf * 2 + hs0) * HS + (pi * 18 + slot) * 8 + lo8] = f2bf(vv);
        }
      }
    }
  }
  __syncthreads();

  // ---- Phase C: conv3 (verified structure; half H -> hseg H*4+quad)
  int a3off[4];
#pragma unroll
  for (int mf = 0; mf < 4; ++mf) {
    const int px = mf * 16 + l16;
    a3off[mf] = quad * HS + (((px >> 3) * 2) * 18 + (px & 7)) * 8;
  }
  floatx4 acc3[4][2];
#pragma unroll
  for (int mf = 0; mf < 4; ++mf) {
    acc3[mf][0] = (floatx4){0.f, 0.f, 0.f, 0.f};
    acc3[mf][1] = (floatx4){0.f, 0.f, 0.f, 0.f};
  }
  short8 b3c0, b3c1, b3n0, b3n1;
  {
    const int kg = quad;  // u=0: tap=0, H=0
    b3c0 = *(const short8*)(bp3 + ((size_t)kg * 128 + wave * 32 + l16) * 8);
    b3c1 =
        *(const short8*)(bp3 + ((size_t)kg * 128 + wave * 32 + 16 + l16) * 8);
  }
#pragma unroll
  for (int u = 0; u < 18; ++u) {
    const int H = u / 9, tap = u % 9;
    const int kh = tap / 3, kw = tap % 3;
    if (u + 1 < 18) {
      const int H2 = (u + 1) / 9, tap2 = (u + 1) % 9;
      const int kg = tap2 * 8 + H2 * 4 + quad;
      b3n0 = *(const short8*)(bp3 + ((size_t)kg * 128 + wave * 32 + l16) * 8);
      b3n1 = *(const short8*)(bp3 +
                              ((size_t)kg * 128 + wave * 32 + 16 + l16) * 8);
    }
    // half H = 4 hsegs = 4*HS shorts
    const int toff = (kh * 18 + (kw >> 1) + (kw & 1) * 9) * 8 + H * 4 * HS;
    __builtin_amdgcn_s_setprio(1);
#pragma unroll
    for (int mf = 0; mf < 4; ++mf) {
      const short8 a = *(const short8*)(&c2o[a3off[mf] + toff]);
      acc3[mf][0] = __builtin_amdgcn_mfma_f32_16x16x32_bf16(
          a, b3c0, acc3[mf][0], 0, 0, 0);
      acc3[mf][1] = __builtin_amdgcn_mfma_f32_16x16x32_bf16(
          a, b3c1, acc3[mf][1], 0, 0, 0);
    }
    __builtin_amdgcn_s_setprio(0);
    b3c0 = b3n0; b3c1 = b3n1;
  }

  // ---- BN3 (inline fold) + ReLU + pool (waves own disjoint 32-ch slices)
  const float alpha3 = red[10] / fmaxf(red[9], 1.f);
#pragma unroll
  for (int nf = 0; nf < 2; ++nf) {
    const int ch = wave * 32 + nf * 16 + l16;
    const float inv = g3[ch] / sqrtf(v3[ch] + 1e-5f);
    const float scv = alpha3 * inv, bsv = b3[ch] - m3[ch] * inv;
    float s = 0.f;
#pragma unroll
    for (int mf = 0; mf < 4; ++mf)
#pragma unroll
      for (int rr = 0; rr < 4; ++rr)
        s += fmaxf(acc3[mf][nf][rr] * scv + bsv, 0.f);
    s += __shfl_xor(s, 16);
    s += __shfl_xor(s, 32);
    if (lane < 16) pbuf[ch] = s;
  }
  __syncthreads();
  if (t < 128) atomicAdd(&pooled[(size_t)img * 128 + t], pbuf[t]);
}

// ---------------------------------------------------------------- linear
// pooled holds SUMS over 3136 px; ql holds signs; alpha_l from red.
__global__ void linear_kernel(const float* __restrict__ pooled,
                              const float* __restrict__ ql,
                              const float* __restrict__ bl,
                              const float* __restrict__ red,
                              float* __restrict__ out) {
  const int idx = blockIdx.x * blockDim.x + threadIdx.x;
  if (idx >= 64 * 10) return;
  const int n = idx / 10, o = idx % 10;
  const float* p = pooled + (size_t)n * 128;
  const float* w = ql + (size_t)o * 128;
  float s = 0.f;
#pragma unroll 4
  for (int c = 0; c < 128; ++c) s += p[c] * w[c];
  const float alpha_l = red[14] / fmaxf(red[13], 1.f);
  out[idx] = s * (alpha_l / 3136.f) + bl[o];
}

// ---------------------------------------------------------------- launch
extern "C" void kernel_launch(void* const* d_in, const int* in_sizes, int n_in,
                              void* d_out, int out_size, void* d_ws,
                              size_t ws_size, hipStream_t stream) {
  const float* x  = (const float*)d_in[0];
  const float* w1 = (const float*)d_in[1];
  const float* g1 = (const float*)d_in[2];
  const float* b1 = (const float*)d_in[3];
  const float* m1 = (const float*)d_in[4];
  const float* v1 = (const float*)d_in[5];
  const float* w2 = (const float*)d_in[6];
  const float* g2 = (const float*)d_in[7];
  const float* b2 = (const float*)d_in[8];
  const float* m2 = (const float*)d_in[9];
  const float* v2 = (const float*)d_in[10];
  const float* w3 = (const float*)d_in[11];
  const float* g3 = (const float*)d_in[12];
  const float* b3 = (const float*)d_in[13];
  const float* m3 = (const float*)d_in[14];
  const float* v3 = (const float*)d_in[15];
  const float* wl = (const float*)d_in[16];
  const float* bl = (const float*)d_in[17];
  float* out = (float*)d_out;

  // ---- workspace layout (red/pooled/bp1 contiguous -> one zeroing memset)
  float* Wf = (float*)d_ws;
  float* red = Wf;                        // 16
  float* pooled = red + 16;               // 8192
  float* bp1f = pooled + 8192;            // 512 floats = 1024 shorts (K32xN32)
  float* ql = bp1f + 512;                 // 1280
  unsigned short* bp1 = (unsigned short*)bp1f;
  unsigned short* Us = (unsigned short*)(ql + 1280);
  unsigned short* bp2 = Us;                 // 18432
  unsigned short* bp3 = bp2 + 18432;        // 73728
  unsigned short* act1 = bp3 + 73728;       // 64*12544*32 = 25690112
  // act2 eliminated (conv2+conv3 fused); total ~52 MB < ws_size

  // ---- prep: memset + 2 reduction/pack phases (BN fold inline) ----
  hipMemsetAsync(red, 0, (16 + 8192 + 512) * sizeof(float), stream);
  tern_phase1<<<dim3(288, 4), 256, 0, stream>>>(w1, w2, w3, wl, 864, 18432,
                                                73728, 1280, red);
  tern_phase2<<<dim3(288, 4), 256, 0, stream>>>(w1, w2, w3, wl, 864, 18432,
                                                73728, 1280, red, bp1, bp2,
                                                bp3, ql);

  // ---- network ----
  conv1_mfma<<<dim3(98, 64), 256, 0, stream>>>(x, bp1, g1, b1, m1, v1, red,
                                               act1);
  conv23_fused<<<dim3(49, 64), 256, 0, stream>>>(act1, bp2, bp3, g2, b2, m2,
                                                 v2, g3, b3, m3, v3, red,
                                                 pooled);
  linear_kernel<<<3, 256, 0, stream>>>(pooled, ql, bl, red, out);
}